// Round 11
// baseline (712.477 us; speedup 1.0000x reference)
//
#include <hip/hip_runtime.h>

#define FIN 6
#define HC 64
#define LAYERS 3

__global__ void PathfindingGNN_17274358464713_kernel() {}

__global__ __launch_bounds__(256) void k_zero(int* __restrict__ p, int n) {
  int i = blockIdx.x * 256 + threadIdx.x;
  if (i < n) p[i] = 0;
}

// ---------------- fused: edge histogram + encoder (independent work, one grid) ----------------
__global__ __launch_bounds__(256) void k_enc_hist(const float* __restrict__ x,
                                                  const float* __restrict__ W,
                                                  const float* __restrict__ b,
                                                  float* __restrict__ h, int Nn,
                                                  const int* __restrict__ dst,
                                                  int* __restrict__ counts, int E, int histB) {
  if ((int)blockIdx.x < histB) {
    int e = blockIdx.x * 256 + threadIdx.x;
    if (e < E) atomicAdd(&counts[dst[e]], 1);
    return;
  }
  int idx = (blockIdx.x - histB) * 256 + threadIdx.x;
  if (idx >= Nn * HC) return;
  int n = idx >> 6, c = idx & 63;
  float s = b[c];
#pragma unroll
  for (int f = 0; f < FIN; ++f)
    s = fmaf(x[n * FIN + f], W[f * HC + c], s);
  h[idx] = s;
}

// ---------------- CSR scan ----------------
__global__ __launch_bounds__(256) void k_scan1(const int* __restrict__ counts, int* __restrict__ partial,
                                               int* __restrict__ blockSums, int n) {
  __shared__ int lds[256];
  int tid = threadIdx.x;
  int base = blockIdx.x * 2048 + tid * 8;
  int v[8], e[8], s = 0;
#pragma unroll
  for (int j = 0; j < 8; ++j) {
    v[j] = (base + j < n) ? counts[base + j] : 0;
    e[j] = s;
    s += v[j];
  }
  lds[tid] = s;
  __syncthreads();
  for (int d = 1; d < 256; d <<= 1) {
    int t = (tid >= d) ? lds[tid - d] : 0;
    __syncthreads();
    lds[tid] += t;
    __syncthreads();
  }
  int off = (tid == 0) ? 0 : lds[tid - 1];
#pragma unroll
  for (int j = 0; j < 8; ++j)
    if (base + j < n) partial[base + j] = off + e[j];
  if (tid == 0) blockSums[blockIdx.x] = lds[255];
}

__global__ __launch_bounds__(256) void k_scan2(const int* __restrict__ blockSums, int* __restrict__ blockOff, int nb) {
  __shared__ int lds[256];
  int tid = threadIdx.x;
  lds[tid] = (tid < nb) ? blockSums[tid] : 0;
  __syncthreads();
  for (int d = 1; d < 256; d <<= 1) {
    int t = (tid >= d) ? lds[tid - d] : 0;
    __syncthreads();
    lds[tid] += t;
    __syncthreads();
  }
  if (tid < nb) blockOff[tid] = (tid == 0) ? 0 : lds[tid - 1];
}

__global__ __launch_bounds__(256) void k_scan3(int* __restrict__ rp, const int* __restrict__ boff,
                                               int* __restrict__ cursor, int n, int total) {
  int i = blockIdx.x * 256 + threadIdx.x;
  if (i > n) return;
  int v = (i == n) ? total : rp[i] + boff[i >> 11];
  rp[i] = v;
  cursor[i] = v;
}

// ---------------- scatter: 4B packed record  src(17b) | q15(ea)<<17 ----------------
__global__ __launch_bounds__(256) void k_scatter(const int* __restrict__ src, const int* __restrict__ dst,
                                                 const float* __restrict__ ea, int* __restrict__ cursor,
                                                 unsigned int* __restrict__ csr, int E) {
  int e = blockIdx.x * 256 + threadIdx.x;
  if (e >= E) return;
  int d = dst[e];
  int p = atomicAdd(&cursor[d], 1);
  unsigned int q = (unsigned int)(ea[e] * 32767.0f + 0.5f);  // ea in [0,1)
  csr[p] = (unsigned int)src[e] | (q << 17);
}

// ---------------- fused layer: CSR aggregate-max + update GEMM + BN (+predictor on last) ----
// 64 nodes/block, 256 threads. Wave-per-node serial edge loop, 4 independent max chains.
__global__ __launch_bounds__(256) void k_layer(const float* __restrict__ h, const int* __restrict__ row_ptr,
                                               const unsigned int* __restrict__ csr,
                                               const float* __restrict__ We, const float* __restrict__ be,
                                               const float* __restrict__ W, const float* __restrict__ b,
                                               const float* __restrict__ gam, const float* __restrict__ bet,
                                               const float* __restrict__ mean, const float* __restrict__ var,
                                               float* __restrict__ out, int Nn,
                                               int last, const float* __restrict__ Wp1,
                                               const float* __restrict__ bp1, const float* __restrict__ Wp2,
                                               const float* __restrict__ bp2, float* __restrict__ pred) {
  __shared__ float Asm[64][68];
  __shared__ float Wsm[64][64];
  __shared__ float red[64][17];
  int tid = threadIdx.x;
  int nb = blockIdx.x * 64;
  int c = tid & 63, w = tid >> 6;
  const float inv15 = 1.0f / 32767.0f;

  // stage W rows 64..127 (agg half) while gathers run
  for (int i = tid; i < 4096; i += 256) Wsm[i >> 6][i & 63] = W[4096 + i];

  float we = We[c], bev = be[c];
  for (int i = 0; i < 16; ++i) {
    int nl = w * 16 + i;
    int nc = min(nb + nl, Nn - 1);
    int r0 = row_ptr[nc], r1 = row_ptr[nc + 1];
    float m0 = -INFINITY, m1 = -INFINITY, m2 = -INFINITY, m3 = -INFINITY;
    int r = r0;
    for (; r + 3 < r1; r += 4) {  // 4 independent gathers in flight
      unsigned int va = __builtin_nontemporal_load(&csr[r]);
      unsigned int vb = __builtin_nontemporal_load(&csr[r + 1]);
      unsigned int vc = __builtin_nontemporal_load(&csr[r + 2]);
      unsigned int vd = __builtin_nontemporal_load(&csr[r + 3]);
      float ha = h[(va & 0x1FFFFu) * HC + c];
      float hb = h[(vb & 0x1FFFFu) * HC + c];
      float hc2 = h[(vc & 0x1FFFFu) * HC + c];
      float hd = h[(vd & 0x1FFFFu) * HC + c];
      m0 = fmaxf(m0, ha * fmaf((float)(va >> 17) * inv15, we, bev));
      m1 = fmaxf(m1, hb * fmaf((float)(vb >> 17) * inv15, we, bev));
      m2 = fmaxf(m2, hc2 * fmaf((float)(vc >> 17) * inv15, we, bev));
      m3 = fmaxf(m3, hd * fmaf((float)(vd >> 17) * inv15, we, bev));
    }
    for (; r < r1; ++r) {
      unsigned int va = __builtin_nontemporal_load(&csr[r]);
      m0 = fmaxf(m0, h[(va & 0x1FFFFu) * HC + c] * fmaf((float)(va >> 17) * inv15, we, bev));
    }
    float m = fmaxf(fmaxf(m0, m1), fmaxf(m2, m3));
    Asm[nl][c] = (m == -INFINITY) ? 0.0f : m;  // empty segment -> 0
  }
  __syncthreads();

  // GEMM phase 0: acc += agg @ W[64..127]
  int c0 = (tid & 15) * 4, n0 = (tid >> 4) * 4;
  float acc[4][4] = {{0.f}};
#pragma unroll 4
  for (int k = 0; k < 64; k += 4) {
    float a[4][4], wv[4][4];
#pragma unroll
    for (int j = 0; j < 4; ++j) {
      float4 t = *(const float4*)&Asm[n0 + j][k];
      a[j][0] = t.x; a[j][1] = t.y; a[j][2] = t.z; a[j][3] = t.w;
    }
#pragma unroll
    for (int j = 0; j < 4; ++j) {
      float4 t = *(const float4*)&Wsm[k + j][c0];
      wv[j][0] = t.x; wv[j][1] = t.y; wv[j][2] = t.z; wv[j][3] = t.w;
    }
#pragma unroll
    for (int i = 0; i < 4; ++i)
#pragma unroll
      for (int j = 0; j < 4; ++j)
#pragma unroll
        for (int l = 0; l < 4; ++l)
          acc[i][l] = fmaf(a[i][j], wv[j][l], acc[i][l]);
  }
  __syncthreads();

  // GEMM phase 1: Asm = h(self), Wsm = W rows 0..63
  for (int i = tid; i < 4096; i += 256) Wsm[i >> 6][i & 63] = W[i];
#pragma unroll
  for (int i = 0; i < 16; ++i) {
    int nl = i * 4 + w;
    int ng = min(nb + nl, Nn - 1);
    Asm[nl][c] = h[ng * HC + c];
  }
  __syncthreads();
#pragma unroll 4
  for (int k = 0; k < 64; k += 4) {
    float a[4][4], wv[4][4];
#pragma unroll
    for (int j = 0; j < 4; ++j) {
      float4 t = *(const float4*)&Asm[n0 + j][k];
      a[j][0] = t.x; a[j][1] = t.y; a[j][2] = t.z; a[j][3] = t.w;
    }
#pragma unroll
    for (int j = 0; j < 4; ++j) {
      float4 t = *(const float4*)&Wsm[k + j][c0];
      wv[j][0] = t.x; wv[j][1] = t.y; wv[j][2] = t.z; wv[j][3] = t.w;
    }
#pragma unroll
    for (int i = 0; i < 4; ++i)
#pragma unroll
      for (int j = 0; j < 4; ++j)
#pragma unroll
        for (int l = 0; l < 4; ++l)
          acc[i][l] = fmaf(a[i][j], wv[j][l], acc[i][l]);
  }

  float scale[4], shift[4], bias[4];
#pragma unroll
  for (int l = 0; l < 4; ++l) {
    int cc = c0 + l;
    bias[l] = b[cc];
    float sc = gam[cc] * rsqrtf(var[cc] + 1e-5f);
    scale[l] = sc;
    shift[l] = bet[cc] - mean[cc] * sc;
  }
  float o[4][4];
#pragma unroll
  for (int i = 0; i < 4; ++i)
#pragma unroll
    for (int l = 0; l < 4; ++l) {
      float v = fmaxf(acc[i][l] + bias[l], 0.f);
      o[i][l] = fmaxf(fmaf(v, scale[l], shift[l]), 0.f);
    }

  if (!last) {
#pragma unroll
    for (int i = 0; i < 4; ++i) {
      int n = nb + n0 + i;
      if (n < Nn)
        *(float4*)&out[n * HC + c0] = make_float4(o[i][0], o[i][1], o[i][2], o[i][3]);
    }
    return;
  }

  // ---- last layer: fused predictor ----
  __syncthreads();
#pragma unroll
  for (int i = 0; i < 4; ++i)
    *(float4*)&Asm[n0 + i][c0] = make_float4(o[i][0], o[i][1], o[i][2], o[i][3]);
  for (int i = tid; i < 4096; i += 256) Wsm[i >> 6][i & 63] = Wp1[i];
  __syncthreads();
  float acc2[4][4] = {{0.f}};
#pragma unroll 4
  for (int k = 0; k < 64; k += 4) {
    float a[4][4], wv[4][4];
#pragma unroll
    for (int j = 0; j < 4; ++j) {
      float4 t = *(const float4*)&Asm[n0 + j][k];
      a[j][0] = t.x; a[j][1] = t.y; a[j][2] = t.z; a[j][3] = t.w;
    }
#pragma unroll
    for (int j = 0; j < 4; ++j) {
      float4 t = *(const float4*)&Wsm[k + j][c0];
      wv[j][0] = t.x; wv[j][1] = t.y; wv[j][2] = t.z; wv[j][3] = t.w;
    }
#pragma unroll
    for (int i = 0; i < 4; ++i)
#pragma unroll
      for (int j = 0; j < 4; ++j)
#pragma unroll
        for (int l = 0; l < 4; ++l)
          acc2[i][l] = fmaf(a[i][j], wv[j][l], acc2[i][l]);
  }
  float bias2[4], w2[4];
#pragma unroll
  for (int l = 0; l < 4; ++l) {
    bias2[l] = bp1[c0 + l];
    w2[l] = Wp2[c0 + l];
  }
#pragma unroll
  for (int i = 0; i < 4; ++i) {
    float s = 0.f;
#pragma unroll
    for (int l = 0; l < 4; ++l) {
      float t = fmaxf(acc2[i][l] + bias2[l], 0.f);
      s = fmaf(t, w2[l], s);
    }
    red[n0 + i][tid & 15] = s;
  }
  __syncthreads();
  if (tid < 64) {
    float s = bp2[0];
#pragma unroll
    for (int g = 0; g < 16; ++g) s += red[tid][g];
    int n = nb + tid;
    if (n < Nn) pred[n] = s;
  }
}

extern "C" void kernel_launch(void* const* d_in, const int* in_sizes, int n_in,
                              void* d_out, int out_size, void* d_ws, size_t ws_size,
                              hipStream_t stream) {
  const float* x = (const float*)d_in[0];
  const int* eidx = (const int*)d_in[1];
  const float* eattr = (const float*)d_in[2];
  const float* Wenc = (const float*)d_in[3];
  const float* benc = (const float*)d_in[4];
  const float* Wedge = (const float*)d_in[5];
  const float* bedge = (const float*)d_in[6];
  const float* Wupd = (const float*)d_in[7];
  const float* bupd = (const float*)d_in[8];
  const float* bng = (const float*)d_in[9];
  const float* bnb = (const float*)d_in[10];
  const float* bnm = (const float*)d_in[11];
  const float* bnv = (const float*)d_in[12];
  const float* Wp1 = (const float*)d_in[13];
  const float* bp1 = (const float*)d_in[14];
  const float* Wp2 = (const float*)d_in[15];
  const float* bp2 = (const float*)d_in[16];

  const int Nn = in_sizes[0] / FIN;
  const int E = in_sizes[1] / 2;
  const int* src = eidx;
  const int* dst = eidx + E;
  const int NH = Nn * HC;

  size_t off = 0;
  char* base = (char*)d_ws;
  auto carve = [&](size_t bytes) -> void* {
    void* p = base + off;
    off += (bytes + 255) & ~(size_t)255;
    return p;
  };
  int* row_ptr = (int*)carve((size_t)(Nn + 1) * 4);
  int* cursor = (int*)carve((size_t)(Nn + 1) * 4);
  int* counts = (int*)carve((size_t)(Nn + 1) * 4);
  int* bsums = (int*)carve(256 * 4);
  int* boffs = (int*)carve(256 * 4);
  unsigned int* csr = (unsigned int*)carve((size_t)E * 4);
  float* hA = (float*)carve((size_t)NH * 4);
  float* hB = (float*)carve((size_t)NH * 4);
  if (off > ws_size) return;

  int nhB = (NH + 255) / 256;
  int histB = (E + 255) / 256;
  int scan1B = (Nn + 2047) / 2048;
  int scan3B = (Nn + 1 + 255) / 256;
  int updB = (Nn + 63) / 64;

  k_zero<<<scan3B, 256, 0, stream>>>(counts, Nn + 1);
  k_enc_hist<<<histB + nhB, 256, 0, stream>>>(x, Wenc, benc, hA, Nn, dst, counts, E, histB);
  k_scan1<<<scan1B, 256, 0, stream>>>(counts, row_ptr, bsums, Nn);
  k_scan2<<<1, 256, 0, stream>>>(bsums, boffs, scan1B);
  k_scan3<<<scan3B, 256, 0, stream>>>(row_ptr, boffs, cursor, Nn, E);
  k_scatter<<<histB, 256, 0, stream>>>(src, dst, eattr, cursor, csr, E);

  float* hc = hA;
  float* hn = hB;
  for (int i = 0; i < LAYERS; ++i) {
    int last = (i == LAYERS - 1) ? 1 : 0;
    k_layer<<<updB, 256, 0, stream>>>(hc, row_ptr, csr,
                                      Wedge + i * HC, bedge + i * HC,
                                      Wupd + i * 2 * HC * HC, bupd + i * HC,
                                      bng + i * HC, bnb + i * HC, bnm + i * HC, bnv + i * HC,
                                      hn, Nn,
                                      last, Wp1, bp1, Wp2, bp2, (float*)d_out);
    float* t = hc; hc = hn; hn = t;
  }
}

// Round 12
// 609.317 us; speedup vs baseline: 1.1693x; 1.1693x over previous
//
#include <hip/hip_runtime.h>
#include <hip/hip_fp16.h>

#define FIN 6
#define HC 64
#define LAYERS 3

__global__ void PathfindingGNN_17274358464713_kernel() {}

__global__ __launch_bounds__(256) void k_zero(int* __restrict__ p, int n) {
  int i = blockIdx.x * 256 + threadIdx.x;
  if (i < n) p[i] = 0;
}

// ---------------- fused: edge histogram + encoder (writes fp32 h and fp16 mirror) ----------
__global__ __launch_bounds__(256) void k_enc_hist(const float* __restrict__ x,
                                                  const float* __restrict__ W,
                                                  const float* __restrict__ b,
                                                  float* __restrict__ h, __half* __restrict__ h16,
                                                  int Nn,
                                                  const int* __restrict__ dst,
                                                  int* __restrict__ counts, int E, int histB) {
  if ((int)blockIdx.x < histB) {
    int e = blockIdx.x * 256 + threadIdx.x;
    if (e < E) atomicAdd(&counts[dst[e]], 1);
    return;
  }
  int idx = (blockIdx.x - histB) * 256 + threadIdx.x;
  if (idx >= Nn * HC) return;
  int n = idx >> 6, c = idx & 63;
  float s = b[c];
#pragma unroll
  for (int f = 0; f < FIN; ++f)
    s = fmaf(x[n * FIN + f], W[f * HC + c], s);
  h[idx] = s;
  h16[idx] = __float2half(s);
}

// ---------------- CSR scan ----------------
__global__ __launch_bounds__(256) void k_scan1(const int* __restrict__ counts, int* __restrict__ partial,
                                               int* __restrict__ blockSums, int n) {
  __shared__ int lds[256];
  int tid = threadIdx.x;
  int base = blockIdx.x * 2048 + tid * 8;
  int v[8], e[8], s = 0;
#pragma unroll
  for (int j = 0; j < 8; ++j) {
    v[j] = (base + j < n) ? counts[base + j] : 0;
    e[j] = s;
    s += v[j];
  }
  lds[tid] = s;
  __syncthreads();
  for (int d = 1; d < 256; d <<= 1) {
    int t = (tid >= d) ? lds[tid - d] : 0;
    __syncthreads();
    lds[tid] += t;
    __syncthreads();
  }
  int off = (tid == 0) ? 0 : lds[tid - 1];
#pragma unroll
  for (int j = 0; j < 8; ++j)
    if (base + j < n) partial[base + j] = off + e[j];
  if (tid == 0) blockSums[blockIdx.x] = lds[255];
}

__global__ __launch_bounds__(256) void k_scan2(const int* __restrict__ blockSums, int* __restrict__ blockOff, int nb) {
  __shared__ int lds[256];
  int tid = threadIdx.x;
  lds[tid] = (tid < nb) ? blockSums[tid] : 0;
  __syncthreads();
  for (int d = 1; d < 256; d <<= 1) {
    int t = (tid >= d) ? lds[tid - d] : 0;
    __syncthreads();
    lds[tid] += t;
    __syncthreads();
  }
  if (tid < nb) blockOff[tid] = (tid == 0) ? 0 : lds[tid - 1];
}

__global__ __launch_bounds__(256) void k_scan3(int* __restrict__ rp, const int* __restrict__ boff,
                                               int* __restrict__ cursor, int n, int total) {
  int i = blockIdx.x * 256 + threadIdx.x;
  if (i > n) return;
  int v = (i == n) ? total : rp[i] + boff[i >> 11];
  rp[i] = v;
  cursor[i] = v;
}

// ---------------- scatter: 4B packed record  src(17b) | q15(ea)<<17 ----------------
__global__ __launch_bounds__(256) void k_scatter(const int* __restrict__ src, const int* __restrict__ dst,
                                                 const float* __restrict__ ea, int* __restrict__ cursor,
                                                 unsigned int* __restrict__ csr, int E) {
  int e = blockIdx.x * 256 + threadIdx.x;
  if (e >= E) return;
  int d = dst[e];
  int p = atomicAdd(&cursor[d], 1);
  unsigned int q = (unsigned int)(ea[e] * 32767.0f + 0.5f);  // ea in [0,1)
  csr[p] = (unsigned int)src[e] | (q << 17);
}

// ---------------- fused layer: fp16-gather aggregate-max + update GEMM + BN (+predictor) ----
// 64 nodes/block, 256 threads. Wave-per-node serial edge loop, 4 independent max chains.
__global__ __launch_bounds__(256) void k_layer(const float* __restrict__ h,
                                               const __half* __restrict__ h16,
                                               const int* __restrict__ row_ptr,
                                               const unsigned int* __restrict__ csr,
                                               const float* __restrict__ We, const float* __restrict__ be,
                                               const float* __restrict__ W, const float* __restrict__ b,
                                               const float* __restrict__ gam, const float* __restrict__ bet,
                                               const float* __restrict__ mean, const float* __restrict__ var,
                                               float* __restrict__ out, __half* __restrict__ out16, int Nn,
                                               int last, const float* __restrict__ Wp1,
                                               const float* __restrict__ bp1, const float* __restrict__ Wp2,
                                               const float* __restrict__ bp2, float* __restrict__ pred) {
  __shared__ float Asm[64][68];
  __shared__ float Wsm[64][64];
  __shared__ float red[64][17];
  int tid = threadIdx.x;
  int nb = blockIdx.x * 64;
  int c = tid & 63, w = tid >> 6;
  const float inv15 = 1.0f / 32767.0f;

  // stage W rows 64..127 (agg half) while gathers run
  for (int i = tid; i < 4096; i += 256) Wsm[i >> 6][i & 63] = W[4096 + i];

  float we = We[c], bev = be[c];
  for (int i = 0; i < 16; ++i) {
    int nl = w * 16 + i;
    int nc = min(nb + nl, Nn - 1);
    int r0 = row_ptr[nc], r1 = row_ptr[nc + 1];
    float m0 = -INFINITY, m1 = -INFINITY, m2 = -INFINITY, m3 = -INFINITY;
    int r = r0;
    for (; r + 3 < r1; r += 4) {  // 4 independent fp16 gathers in flight
      unsigned int va = csr[r], vb = csr[r + 1], vc = csr[r + 2], vd = csr[r + 3];
      float ha = __half2float(h16[(va & 0x1FFFFu) * HC + c]);
      float hb = __half2float(h16[(vb & 0x1FFFFu) * HC + c]);
      float hc2 = __half2float(h16[(vc & 0x1FFFFu) * HC + c]);
      float hd = __half2float(h16[(vd & 0x1FFFFu) * HC + c]);
      m0 = fmaxf(m0, ha * fmaf((float)(va >> 17) * inv15, we, bev));
      m1 = fmaxf(m1, hb * fmaf((float)(vb >> 17) * inv15, we, bev));
      m2 = fmaxf(m2, hc2 * fmaf((float)(vc >> 17) * inv15, we, bev));
      m3 = fmaxf(m3, hd * fmaf((float)(vd >> 17) * inv15, we, bev));
    }
    for (; r < r1; ++r) {
      unsigned int va = csr[r];
      m0 = fmaxf(m0, __half2float(h16[(va & 0x1FFFFu) * HC + c]) *
                         fmaf((float)(va >> 17) * inv15, we, bev));
    }
    float m = fmaxf(fmaxf(m0, m1), fmaxf(m2, m3));
    Asm[nl][c] = (m == -INFINITY) ? 0.0f : m;  // empty segment -> 0
  }
  __syncthreads();

  // GEMM phase 0: acc += agg @ W[64..127]
  int c0 = (tid & 15) * 4, n0 = (tid >> 4) * 4;
  float acc[4][4] = {{0.f}};
#pragma unroll 4
  for (int k = 0; k < 64; k += 4) {
    float a[4][4], wv[4][4];
#pragma unroll
    for (int j = 0; j < 4; ++j) {
      float4 t = *(const float4*)&Asm[n0 + j][k];
      a[j][0] = t.x; a[j][1] = t.y; a[j][2] = t.z; a[j][3] = t.w;
    }
#pragma unroll
    for (int j = 0; j < 4; ++j) {
      float4 t = *(const float4*)&Wsm[k + j][c0];
      wv[j][0] = t.x; wv[j][1] = t.y; wv[j][2] = t.z; wv[j][3] = t.w;
    }
#pragma unroll
    for (int i = 0; i < 4; ++i)
#pragma unroll
      for (int j = 0; j < 4; ++j)
#pragma unroll
        for (int l = 0; l < 4; ++l)
          acc[i][l] = fmaf(a[i][j], wv[j][l], acc[i][l]);
  }
  __syncthreads();

  // GEMM phase 1: Asm = h(self, fp32), Wsm = W rows 0..63
  for (int i = tid; i < 4096; i += 256) Wsm[i >> 6][i & 63] = W[i];
#pragma unroll
  for (int i = 0; i < 16; ++i) {
    int nl = i * 4 + w;
    int ng = min(nb + nl, Nn - 1);
    Asm[nl][c] = h[ng * HC + c];
  }
  __syncthreads();
#pragma unroll 4
  for (int k = 0; k < 64; k += 4) {
    float a[4][4], wv[4][4];
#pragma unroll
    for (int j = 0; j < 4; ++j) {
      float4 t = *(const float4*)&Asm[n0 + j][k];
      a[j][0] = t.x; a[j][1] = t.y; a[j][2] = t.z; a[j][3] = t.w;
    }
#pragma unroll
    for (int j = 0; j < 4; ++j) {
      float4 t = *(const float4*)&Wsm[k + j][c0];
      wv[j][0] = t.x; wv[j][1] = t.y; wv[j][2] = t.z; wv[j][3] = t.w;
    }
#pragma unroll
    for (int i = 0; i < 4; ++i)
#pragma unroll
      for (int j = 0; j < 4; ++j)
#pragma unroll
        for (int l = 0; l < 4; ++l)
          acc[i][l] = fmaf(a[i][j], wv[j][l], acc[i][l]);
  }

  float scale[4], shift[4], bias[4];
#pragma unroll
  for (int l = 0; l < 4; ++l) {
    int cc = c0 + l;
    bias[l] = b[cc];
    float sc = gam[cc] * rsqrtf(var[cc] + 1e-5f);
    scale[l] = sc;
    shift[l] = bet[cc] - mean[cc] * sc;
  }
  float o[4][4];
#pragma unroll
  for (int i = 0; i < 4; ++i)
#pragma unroll
    for (int l = 0; l < 4; ++l) {
      float v = fmaxf(acc[i][l] + bias[l], 0.f);
      o[i][l] = fmaxf(fmaf(v, scale[l], shift[l]), 0.f);
    }

  if (!last) {
#pragma unroll
    for (int i = 0; i < 4; ++i) {
      int n = nb + n0 + i;
      if (n < Nn) {
        *(float4*)&out[n * HC + c0] = make_float4(o[i][0], o[i][1], o[i][2], o[i][3]);
        __half2 p0 = __floats2half2_rn(o[i][0], o[i][1]);
        __half2 p1 = __floats2half2_rn(o[i][2], o[i][3]);
        *(__half2*)&out16[n * HC + c0] = p0;
        *(__half2*)&out16[n * HC + c0 + 2] = p1;
      }
    }
    return;
  }

  // ---- last layer: fused predictor ----
  __syncthreads();
#pragma unroll
  for (int i = 0; i < 4; ++i)
    *(float4*)&Asm[n0 + i][c0] = make_float4(o[i][0], o[i][1], o[i][2], o[i][3]);
  for (int i = tid; i < 4096; i += 256) Wsm[i >> 6][i & 63] = Wp1[i];
  __syncthreads();
  float acc2[4][4] = {{0.f}};
#pragma unroll 4
  for (int k = 0; k < 64; k += 4) {
    float a[4][4], wv[4][4];
#pragma unroll
    for (int j = 0; j < 4; ++j) {
      float4 t = *(const float4*)&Asm[n0 + j][k];
      a[j][0] = t.x; a[j][1] = t.y; a[j][2] = t.z; a[j][3] = t.w;
    }
#pragma unroll
    for (int j = 0; j < 4; ++j) {
      float4 t = *(const float4*)&Wsm[k + j][c0];
      wv[j][0] = t.x; wv[j][1] = t.y; wv[j][2] = t.z; wv[j][3] = t.w;
    }
#pragma unroll
    for (int i = 0; i < 4; ++i)
#pragma unroll
      for (int j = 0; j < 4; ++j)
#pragma unroll
        for (int l = 0; l < 4; ++l)
          acc2[i][l] = fmaf(a[i][j], wv[j][l], acc2[i][l]);
  }
  float bias2[4], w2[4];
#pragma unroll
  for (int l = 0; l < 4; ++l) {
    bias2[l] = bp1[c0 + l];
    w2[l] = Wp2[c0 + l];
  }
#pragma unroll
  for (int i = 0; i < 4; ++i) {
    float s = 0.f;
#pragma unroll
    for (int l = 0; l < 4; ++l) {
      float t = fmaxf(acc2[i][l] + bias2[l], 0.f);
      s = fmaf(t, w2[l], s);
    }
    red[n0 + i][tid & 15] = s;
  }
  __syncthreads();
  if (tid < 64) {
    float s = bp2[0];
#pragma unroll
    for (int g = 0; g < 16; ++g) s += red[tid][g];
    int n = nb + tid;
    if (n < Nn) pred[n] = s;
  }
}

extern "C" void kernel_launch(void* const* d_in, const int* in_sizes, int n_in,
                              void* d_out, int out_size, void* d_ws, size_t ws_size,
                              hipStream_t stream) {
  const float* x = (const float*)d_in[0];
  const int* eidx = (const int*)d_in[1];
  const float* eattr = (const float*)d_in[2];
  const float* Wenc = (const float*)d_in[3];
  const float* benc = (const float*)d_in[4];
  const float* Wedge = (const float*)d_in[5];
  const float* bedge = (const float*)d_in[6];
  const float* Wupd = (const float*)d_in[7];
  const float* bupd = (const float*)d_in[8];
  const float* bng = (const float*)d_in[9];
  const float* bnb = (const float*)d_in[10];
  const float* bnm = (const float*)d_in[11];
  const float* bnv = (const float*)d_in[12];
  const float* Wp1 = (const float*)d_in[13];
  const float* bp1 = (const float*)d_in[14];
  const float* Wp2 = (const float*)d_in[15];
  const float* bp2 = (const float*)d_in[16];

  const int Nn = in_sizes[0] / FIN;
  const int E = in_sizes[1] / 2;
  const int* src = eidx;
  const int* dst = eidx + E;
  const int NH = Nn * HC;

  size_t off = 0;
  char* base = (char*)d_ws;
  auto carve = [&](size_t bytes) -> void* {
    void* p = base + off;
    off += (bytes + 255) & ~(size_t)255;
    return p;
  };
  int* row_ptr = (int*)carve((size_t)(Nn + 1) * 4);
  int* cursor = (int*)carve((size_t)(Nn + 1) * 4);
  int* counts = (int*)carve((size_t)(Nn + 1) * 4);
  int* bsums = (int*)carve(256 * 4);
  int* boffs = (int*)carve(256 * 4);
  unsigned int* csr = (unsigned int*)carve((size_t)E * 4);
  float* hA = (float*)carve((size_t)NH * 4);
  float* hB = (float*)carve((size_t)NH * 4);
  __half* hA16 = (__half*)carve((size_t)NH * 2);
  __half* hB16 = (__half*)carve((size_t)NH * 2);
  if (off > ws_size) return;

  int nhB = (NH + 255) / 256;
  int histB = (E + 255) / 256;
  int scan1B = (Nn + 2047) / 2048;
  int scan3B = (Nn + 1 + 255) / 256;
  int updB = (Nn + 63) / 64;

  k_zero<<<scan3B, 256, 0, stream>>>(counts, Nn + 1);
  k_enc_hist<<<histB + nhB, 256, 0, stream>>>(x, Wenc, benc, hA, hA16, Nn, dst, counts, E, histB);
  k_scan1<<<scan1B, 256, 0, stream>>>(counts, row_ptr, bsums, Nn);
  k_scan2<<<1, 256, 0, stream>>>(bsums, boffs, scan1B);
  k_scan3<<<scan3B, 256, 0, stream>>>(row_ptr, boffs, cursor, Nn, E);
  k_scatter<<<histB, 256, 0, stream>>>(src, dst, eattr, cursor, csr, E);

  float* hc = hA;
  float* hn = hB;
  __half* hc16 = hA16;
  __half* hn16 = hB16;
  for (int i = 0; i < LAYERS; ++i) {
    int last = (i == LAYERS - 1) ? 1 : 0;
    k_layer<<<updB, 256, 0, stream>>>(hc, hc16, row_ptr, csr,
                                      Wedge + i * HC, bedge + i * HC,
                                      Wupd + i * 2 * HC * HC, bupd + i * HC,
                                      bng + i * HC, bnb + i * HC, bnm + i * HC, bnv + i * HC,
                                      hn, hn16, Nn,
                                      last, Wp1, bp1, Wp2, bp2, (float*)d_out);
    float* t = hc; hc = hn; hn = t;
    __half* t16 = hc16; hc16 = hn16; hn16 = t16;
  }
}

// Round 13
// 534.596 us; speedup vs baseline: 1.3327x; 1.1398x over previous
//
#include <hip/hip_runtime.h>
#include <hip/hip_fp16.h>

#define FIN 6
#define HC 64
#define LAYERS 3

__global__ void PathfindingGNN_17274358464713_kernel() {}

__global__ __launch_bounds__(256) void k_zero(int* __restrict__ p, int n) {
  int i = blockIdx.x * 256 + threadIdx.x;
  if (i < n) p[i] = 0;
}

// ---------------- fused: edge histogram + encoder (writes fp32 h and fp16 mirror) ----------
__global__ __launch_bounds__(256) void k_enc_hist(const float* __restrict__ x,
                                                  const float* __restrict__ W,
                                                  const float* __restrict__ b,
                                                  float* __restrict__ h, __half* __restrict__ h16,
                                                  int Nn,
                                                  const int* __restrict__ dst,
                                                  int* __restrict__ counts, int E, int histB) {
  if ((int)blockIdx.x < histB) {
    int e = blockIdx.x * 256 + threadIdx.x;
    if (e < E) atomicAdd(&counts[dst[e]], 1);
    return;
  }
  int idx = (blockIdx.x - histB) * 256 + threadIdx.x;
  if (idx >= Nn * HC) return;
  int n = idx >> 6, c = idx & 63;
  float s = b[c];
#pragma unroll
  for (int f = 0; f < FIN; ++f)
    s = fmaf(x[n * FIN + f], W[f * HC + c], s);
  h[idx] = s;
  h16[idx] = __float2half(s);
}

// ---------------- CSR scan ----------------
__global__ __launch_bounds__(256) void k_scan1(const int* __restrict__ counts, int* __restrict__ partial,
                                               int* __restrict__ blockSums, int n) {
  __shared__ int lds[256];
  int tid = threadIdx.x;
  int base = blockIdx.x * 2048 + tid * 8;
  int v[8], e[8], s = 0;
#pragma unroll
  for (int j = 0; j < 8; ++j) {
    v[j] = (base + j < n) ? counts[base + j] : 0;
    e[j] = s;
    s += v[j];
  }
  lds[tid] = s;
  __syncthreads();
  for (int d = 1; d < 256; d <<= 1) {
    int t = (tid >= d) ? lds[tid - d] : 0;
    __syncthreads();
    lds[tid] += t;
    __syncthreads();
  }
  int off = (tid == 0) ? 0 : lds[tid - 1];
#pragma unroll
  for (int j = 0; j < 8; ++j)
    if (base + j < n) partial[base + j] = off + e[j];
  if (tid == 0) blockSums[blockIdx.x] = lds[255];
}

__global__ __launch_bounds__(256) void k_scan2(const int* __restrict__ blockSums, int* __restrict__ blockOff, int nb) {
  __shared__ int lds[256];
  int tid = threadIdx.x;
  lds[tid] = (tid < nb) ? blockSums[tid] : 0;
  __syncthreads();
  for (int d = 1; d < 256; d <<= 1) {
    int t = (tid >= d) ? lds[tid - d] : 0;
    __syncthreads();
    lds[tid] += t;
    __syncthreads();
  }
  if (tid < nb) blockOff[tid] = (tid == 0) ? 0 : lds[tid - 1];
}

__global__ __launch_bounds__(256) void k_scan3(int* __restrict__ rp, const int* __restrict__ boff,
                                               int* __restrict__ cursor, int n, int total) {
  int i = blockIdx.x * 256 + threadIdx.x;
  if (i > n) return;
  int v = (i == n) ? total : rp[i] + boff[i >> 11];
  rp[i] = v;
  cursor[i] = v;
}

// ---------------- scatter: 4B packed record  src(17b) | q15(ea)<<17 ----------------
__global__ __launch_bounds__(256) void k_scatter(const int* __restrict__ src, const int* __restrict__ dst,
                                                 const float* __restrict__ ea, int* __restrict__ cursor,
                                                 unsigned int* __restrict__ csr, int E) {
  int e = blockIdx.x * 256 + threadIdx.x;
  if (e >= E) return;
  int d = dst[e];
  int p = atomicAdd(&cursor[d], 1);
  unsigned int q = (unsigned int)(ea[e] * 32767.0f + 0.5f);  // ea in [0,1)
  csr[p] = (unsigned int)src[e] | (q << 17);
}

// ---------------- fused layer: node-paired fp16 aggregate + update GEMM + BN (+predictor) --
// 64 nodes/block, 256 threads. Wave owns 16 nodes, processed as pairs (i, i+8):
// 8 independent gather chains in flight during the joint loop.
__global__ __launch_bounds__(256) void k_layer(const float* __restrict__ h,
                                               const __half* __restrict__ h16,
                                               const int* __restrict__ row_ptr,
                                               const unsigned int* __restrict__ csr,
                                               const float* __restrict__ We, const float* __restrict__ be,
                                               const float* __restrict__ W, const float* __restrict__ b,
                                               const float* __restrict__ gam, const float* __restrict__ bet,
                                               const float* __restrict__ mean, const float* __restrict__ var,
                                               float* __restrict__ out, __half* __restrict__ out16, int Nn,
                                               int last, const float* __restrict__ Wp1,
                                               const float* __restrict__ bp1, const float* __restrict__ Wp2,
                                               const float* __restrict__ bp2, float* __restrict__ pred) {
  __shared__ float Asm[64][68];
  __shared__ float Wsm[64][64];
  __shared__ float red[64][17];
  int tid = threadIdx.x;
  int nb = blockIdx.x * 64;
  int c = tid & 63, w = tid >> 6;
  const float inv15 = 1.0f / 32767.0f;

  // stage W rows 64..127 (agg half) while gathers run
  for (int i = tid; i < 4096; i += 256) Wsm[i >> 6][i & 63] = W[4096 + i];

  float we = We[c], bev = be[c];
  for (int i = 0; i < 8; ++i) {
    int nlA = w * 16 + i;
    int nlB = nlA + 8;
    int ncA = min(nb + nlA, Nn - 1);
    int ncB = min(nb + nlB, Nn - 1);
    int rA = row_ptr[ncA], rA1 = row_ptr[ncA + 1];
    int rB = row_ptr[ncB], rB1 = row_ptr[ncB + 1];
    float A0 = -INFINITY, A1 = -INFINITY, A2 = -INFINITY, A3 = -INFINITY;
    float B0 = -INFINITY, B1 = -INFINITY, B2 = -INFINITY, B3 = -INFINITY;
    // joint loop: 8 gathers in flight
    while ((rA + 3 < rA1) && (rB + 3 < rB1)) {
      unsigned int va0 = csr[rA], va1 = csr[rA + 1], va2 = csr[rA + 2], va3 = csr[rA + 3];
      unsigned int vb0 = csr[rB], vb1 = csr[rB + 1], vb2 = csr[rB + 2], vb3 = csr[rB + 3];
      float ha0 = __half2float(h16[(va0 & 0x1FFFFu) * HC + c]);
      float ha1 = __half2float(h16[(va1 & 0x1FFFFu) * HC + c]);
      float ha2 = __half2float(h16[(va2 & 0x1FFFFu) * HC + c]);
      float ha3 = __half2float(h16[(va3 & 0x1FFFFu) * HC + c]);
      float hb0 = __half2float(h16[(vb0 & 0x1FFFFu) * HC + c]);
      float hb1 = __half2float(h16[(vb1 & 0x1FFFFu) * HC + c]);
      float hb2 = __half2float(h16[(vb2 & 0x1FFFFu) * HC + c]);
      float hb3 = __half2float(h16[(vb3 & 0x1FFFFu) * HC + c]);
      A0 = fmaxf(A0, ha0 * fmaf((float)(va0 >> 17) * inv15, we, bev));
      A1 = fmaxf(A1, ha1 * fmaf((float)(va1 >> 17) * inv15, we, bev));
      A2 = fmaxf(A2, ha2 * fmaf((float)(va2 >> 17) * inv15, we, bev));
      A3 = fmaxf(A3, ha3 * fmaf((float)(va3 >> 17) * inv15, we, bev));
      B0 = fmaxf(B0, hb0 * fmaf((float)(vb0 >> 17) * inv15, we, bev));
      B1 = fmaxf(B1, hb1 * fmaf((float)(vb1 >> 17) * inv15, we, bev));
      B2 = fmaxf(B2, hb2 * fmaf((float)(vb2 >> 17) * inv15, we, bev));
      B3 = fmaxf(B3, hb3 * fmaf((float)(vb3 >> 17) * inv15, we, bev));
      rA += 4;
      rB += 4;
    }
    // drain A
    for (; rA + 3 < rA1; rA += 4) {
      unsigned int va0 = csr[rA], va1 = csr[rA + 1], va2 = csr[rA + 2], va3 = csr[rA + 3];
      float ha0 = __half2float(h16[(va0 & 0x1FFFFu) * HC + c]);
      float ha1 = __half2float(h16[(va1 & 0x1FFFFu) * HC + c]);
      float ha2 = __half2float(h16[(va2 & 0x1FFFFu) * HC + c]);
      float ha3 = __half2float(h16[(va3 & 0x1FFFFu) * HC + c]);
      A0 = fmaxf(A0, ha0 * fmaf((float)(va0 >> 17) * inv15, we, bev));
      A1 = fmaxf(A1, ha1 * fmaf((float)(va1 >> 17) * inv15, we, bev));
      A2 = fmaxf(A2, ha2 * fmaf((float)(va2 >> 17) * inv15, we, bev));
      A3 = fmaxf(A3, ha3 * fmaf((float)(va3 >> 17) * inv15, we, bev));
    }
    for (; rA < rA1; ++rA) {
      unsigned int va = csr[rA];
      A0 = fmaxf(A0, __half2float(h16[(va & 0x1FFFFu) * HC + c]) *
                         fmaf((float)(va >> 17) * inv15, we, bev));
    }
    // drain B
    for (; rB + 3 < rB1; rB += 4) {
      unsigned int vb0 = csr[rB], vb1 = csr[rB + 1], vb2 = csr[rB + 2], vb3 = csr[rB + 3];
      float hb0 = __half2float(h16[(vb0 & 0x1FFFFu) * HC + c]);
      float hb1 = __half2float(h16[(vb1 & 0x1FFFFu) * HC + c]);
      float hb2 = __half2float(h16[(vb2 & 0x1FFFFu) * HC + c]);
      float hb3 = __half2float(h16[(vb3 & 0x1FFFFu) * HC + c]);
      B0 = fmaxf(B0, hb0 * fmaf((float)(vb0 >> 17) * inv15, we, bev));
      B1 = fmaxf(B1, hb1 * fmaf((float)(vb1 >> 17) * inv15, we, bev));
      B2 = fmaxf(B2, hb2 * fmaf((float)(vb2 >> 17) * inv15, we, bev));
      B3 = fmaxf(B3, hb3 * fmaf((float)(vb3 >> 17) * inv15, we, bev));
    }
    for (; rB < rB1; ++rB) {
      unsigned int vb = csr[rB];
      B0 = fmaxf(B0, __half2float(h16[(vb & 0x1FFFFu) * HC + c]) *
                         fmaf((float)(vb >> 17) * inv15, we, bev));
    }
    float mA = fmaxf(fmaxf(A0, A1), fmaxf(A2, A3));
    float mB = fmaxf(fmaxf(B0, B1), fmaxf(B2, B3));
    Asm[nlA][c] = (mA == -INFINITY) ? 0.0f : mA;
    Asm[nlB][c] = (mB == -INFINITY) ? 0.0f : mB;
  }
  __syncthreads();

  // GEMM phase 0: acc += agg @ W[64..127]
  int c0 = (tid & 15) * 4, n0 = (tid >> 4) * 4;
  float acc[4][4] = {{0.f}};
#pragma unroll 4
  for (int k = 0; k < 64; k += 4) {
    float a[4][4], wv[4][4];
#pragma unroll
    for (int j = 0; j < 4; ++j) {
      float4 t = *(const float4*)&Asm[n0 + j][k];
      a[j][0] = t.x; a[j][1] = t.y; a[j][2] = t.z; a[j][3] = t.w;
    }
#pragma unroll
    for (int j = 0; j < 4; ++j) {
      float4 t = *(const float4*)&Wsm[k + j][c0];
      wv[j][0] = t.x; wv[j][1] = t.y; wv[j][2] = t.z; wv[j][3] = t.w;
    }
#pragma unroll
    for (int i = 0; i < 4; ++i)
#pragma unroll
      for (int j = 0; j < 4; ++j)
#pragma unroll
        for (int l = 0; l < 4; ++l)
          acc[i][l] = fmaf(a[i][j], wv[j][l], acc[i][l]);
  }
  __syncthreads();

  // GEMM phase 1: Asm = h(self, fp32), Wsm = W rows 0..63
  for (int i = tid; i < 4096; i += 256) Wsm[i >> 6][i & 63] = W[i];
#pragma unroll
  for (int i = 0; i < 16; ++i) {
    int nl = i * 4 + w;
    int ng = min(nb + nl, Nn - 1);
    Asm[nl][c] = h[ng * HC + c];
  }
  __syncthreads();
#pragma unroll 4
  for (int k = 0; k < 64; k += 4) {
    float a[4][4], wv[4][4];
#pragma unroll
    for (int j = 0; j < 4; ++j) {
      float4 t = *(const float4*)&Asm[n0 + j][k];
      a[j][0] = t.x; a[j][1] = t.y; a[j][2] = t.z; a[j][3] = t.w;
    }
#pragma unroll
    for (int j = 0; j < 4; ++j) {
      float4 t = *(const float4*)&Wsm[k + j][c0];
      wv[j][0] = t.x; wv[j][1] = t.y; wv[j][2] = t.z; wv[j][3] = t.w;
    }
#pragma unroll
    for (int i = 0; i < 4; ++i)
#pragma unroll
      for (int j = 0; j < 4; ++j)
#pragma unroll
        for (int l = 0; l < 4; ++l)
          acc[i][l] = fmaf(a[i][j], wv[j][l], acc[i][l]);
  }

  float scale[4], shift[4], bias[4];
#pragma unroll
  for (int l = 0; l < 4; ++l) {
    int cc = c0 + l;
    bias[l] = b[cc];
    float sc = gam[cc] * rsqrtf(var[cc] + 1e-5f);
    scale[l] = sc;
    shift[l] = bet[cc] - mean[cc] * sc;
  }
  float o[4][4];
#pragma unroll
  for (int i = 0; i < 4; ++i)
#pragma unroll
    for (int l = 0; l < 4; ++l) {
      float v = fmaxf(acc[i][l] + bias[l], 0.f);
      o[i][l] = fmaxf(fmaf(v, scale[l], shift[l]), 0.f);
    }

  if (!last) {
#pragma unroll
    for (int i = 0; i < 4; ++i) {
      int n = nb + n0 + i;
      if (n < Nn) {
        *(float4*)&out[n * HC + c0] = make_float4(o[i][0], o[i][1], o[i][2], o[i][3]);
        __half2 p0 = __floats2half2_rn(o[i][0], o[i][1]);
        __half2 p1 = __floats2half2_rn(o[i][2], o[i][3]);
        *(__half2*)&out16[n * HC + c0] = p0;
        *(__half2*)&out16[n * HC + c0 + 2] = p1;
      }
    }
    return;
  }

  // ---- last layer: fused predictor ----
  __syncthreads();
#pragma unroll
  for (int i = 0; i < 4; ++i)
    *(float4*)&Asm[n0 + i][c0] = make_float4(o[i][0], o[i][1], o[i][2], o[i][3]);
  for (int i = tid; i < 4096; i += 256) Wsm[i >> 6][i & 63] = Wp1[i];
  __syncthreads();
  float acc2[4][4] = {{0.f}};
#pragma unroll 4
  for (int k = 0; k < 64; k += 4) {
    float a[4][4], wv[4][4];
#pragma unroll
    for (int j = 0; j < 4; ++j) {
      float4 t = *(const float4*)&Asm[n0 + j][k];
      a[j][0] = t.x; a[j][1] = t.y; a[j][2] = t.z; a[j][3] = t.w;
    }
#pragma unroll
    for (int j = 0; j < 4; ++j) {
      float4 t = *(const float4*)&Wsm[k + j][c0];
      wv[j][0] = t.x; wv[j][1] = t.y; wv[j][2] = t.z; wv[j][3] = t.w;
    }
#pragma unroll
    for (int i = 0; i < 4; ++i)
#pragma unroll
      for (int j = 0; j < 4; ++j)
#pragma unroll
        for (int l = 0; l < 4; ++l)
          acc2[i][l] = fmaf(a[i][j], wv[j][l], acc2[i][l]);
  }
  float bias2[4], w2[4];
#pragma unroll
  for (int l = 0; l < 4; ++l) {
    bias2[l] = bp1[c0 + l];
    w2[l] = Wp2[c0 + l];
  }
#pragma unroll
  for (int i = 0; i < 4; ++i) {
    float s = 0.f;
#pragma unroll
    for (int l = 0; l < 4; ++l) {
      float t = fmaxf(acc2[i][l] + bias2[l], 0.f);
      s = fmaf(t, w2[l], s);
    }
    red[n0 + i][tid & 15] = s;
  }
  __syncthreads();
  if (tid < 64) {
    float s = bp2[0];
#pragma unroll
    for (int g = 0; g < 16; ++g) s += red[tid][g];
    int n = nb + tid;
    if (n < Nn) pred[n] = s;
  }
}

extern "C" void kernel_launch(void* const* d_in, const int* in_sizes, int n_in,
                              void* d_out, int out_size, void* d_ws, size_t ws_size,
                              hipStream_t stream) {
  const float* x = (const float*)d_in[0];
  const int* eidx = (const int*)d_in[1];
  const float* eattr = (const float*)d_in[2];
  const float* Wenc = (const float*)d_in[3];
  const float* benc = (const float*)d_in[4];
  const float* Wedge = (const float*)d_in[5];
  const float* bedge = (const float*)d_in[6];
  const float* Wupd = (const float*)d_in[7];
  const float* bupd = (const float*)d_in[8];
  const float* bng = (const float*)d_in[9];
  const float* bnb = (const float*)d_in[10];
  const float* bnm = (const float*)d_in[11];
  const float* bnv = (const float*)d_in[12];
  const float* Wp1 = (const float*)d_in[13];
  const float* bp1 = (const float*)d_in[14];
  const float* Wp2 = (const float*)d_in[15];
  const float* bp2 = (const float*)d_in[16];

  const int Nn = in_sizes[0] / FIN;
  const int E = in_sizes[1] / 2;
  const int* src = eidx;
  const int* dst = eidx + E;
  const int NH = Nn * HC;

  size_t off = 0;
  char* base = (char*)d_ws;
  auto carve = [&](size_t bytes) -> void* {
    void* p = base + off;
    off += (bytes + 255) & ~(size_t)255;
    return p;
  };
  int* row_ptr = (int*)carve((size_t)(Nn + 1) * 4);
  int* cursor = (int*)carve((size_t)(Nn + 1) * 4);
  int* counts = (int*)carve((size_t)(Nn + 1) * 4);
  int* bsums = (int*)carve(256 * 4);
  int* boffs = (int*)carve(256 * 4);
  unsigned int* csr = (unsigned int*)carve((size_t)E * 4);
  float* hA = (float*)carve((size_t)NH * 4);
  float* hB = (float*)carve((size_t)NH * 4);
  __half* hA16 = (__half*)carve((size_t)NH * 2);
  __half* hB16 = (__half*)carve((size_t)NH * 2);
  if (off > ws_size) return;

  int nhB = (NH + 255) / 256;
  int histB = (E + 255) / 256;
  int scan1B = (Nn + 2047) / 2048;
  int scan3B = (Nn + 1 + 255) / 256;
  int updB = (Nn + 63) / 64;

  k_zero<<<scan3B, 256, 0, stream>>>(counts, Nn + 1);
  k_enc_hist<<<histB + nhB, 256, 0, stream>>>(x, Wenc, benc, hA, hA16, Nn, dst, counts, E, histB);
  k_scan1<<<scan1B, 256, 0, stream>>>(counts, row_ptr, bsums, Nn);
  k_scan2<<<1, 256, 0, stream>>>(bsums, boffs, scan1B);
  k_scan3<<<scan3B, 256, 0, stream>>>(row_ptr, boffs, cursor, Nn, E);
  k_scatter<<<histB, 256, 0, stream>>>(src, dst, eattr, cursor, csr, E);

  float* hc = hA;
  float* hn = hB;
  __half* hc16 = hA16;
  __half* hn16 = hB16;
  for (int i = 0; i < LAYERS; ++i) {
    int last = (i == LAYERS - 1) ? 1 : 0;
    k_layer<<<updB, 256, 0, stream>>>(hc, hc16, row_ptr, csr,
                                      Wedge + i * HC, bedge + i * HC,
                                      Wupd + i * 2 * HC * HC, bupd + i * HC,
                                      bng + i * HC, bnb + i * HC, bnm + i * HC, bnv + i * HC,
                                      hn, hn16, Nn,
                                      last, Wp1, bp1, Wp2, bp2, (float*)d_out);
    float* t = hc; hc = hn; hn = t;
    __half* t16 = hc16; hc16 = hn16; hn16 = t16;
  }
}